// Round 4
// baseline (1046.193 us; speedup 1.0000x reference)
//
#include <hip/hip_runtime.h>

// MultiEmbedding: y[t] = sum_{l=0..7} weight[l, x[t,l], :]  (D=1024, f32)
// L=8, K=1024, D=1024, T1=T2=65536.
// One block (256 threads) per output row; each thread owns one float4 (4 cols).
// Gather reads (4 GB logical) come from L2/L3 (weight = 32 MB, L3-resident);
// HBM traffic is dominated by the 512 MB output write.
// Single launch covering both x1 and x2 (grid = T1+T2) to avoid two-launch overhead.

#define L_LEVELS 8
#define D_DIM 1024

__global__ __launch_bounds__(256) void multi_embed_kernel(
    const int* __restrict__ x1, const int* __restrict__ x2,
    const float* __restrict__ w, float* __restrict__ out, int T1, int Ttot)
{
    const int row = blockIdx.x;
    if (row >= Ttot) return;

    // Pick which input tensor this row belongs to.
    const int* xi = (row < T1) ? (x1 + (size_t)row * L_LEVELS)
                               : (x2 + (size_t)(row - T1) * L_LEVELS);

    // 8 wave-uniform index loads (same address across lanes -> broadcast)
    int idx[L_LEVELS];
#pragma unroll
    for (int l = 0; l < L_LEVELS; ++l) idx[l] = xi[l];

    const int d4 = threadIdx.x;  // 0..255, each owns float4 = 4 columns

    // Issue all 8 gather loads up front (independent chains -> ILP hides cache latency)
    float4 v[L_LEVELS];
#pragma unroll
    for (int l = 0; l < L_LEVELS; ++l) {
        const float4* wp = reinterpret_cast<const float4*>(
            w + ((size_t)l * 1024 + (size_t)idx[l]) * D_DIM);
        v[l] = wp[d4];
    }

    // Tree-sum
    float4 acc;
    acc.x = ((v[0].x + v[1].x) + (v[2].x + v[3].x)) + ((v[4].x + v[5].x) + (v[6].x + v[7].x));
    acc.y = ((v[0].y + v[1].y) + (v[2].y + v[3].y)) + ((v[4].y + v[5].y) + (v[6].y + v[7].y));
    acc.z = ((v[0].z + v[1].z) + (v[2].z + v[3].z)) + ((v[4].z + v[5].z) + (v[6].z + v[7].z));
    acc.w = ((v[0].w + v[1].w) + (v[2].w + v[3].w)) + ((v[4].w + v[5].w) + (v[6].w + v[7].w));

    reinterpret_cast<float4*>(out + (size_t)row * D_DIM)[d4] = acc;
}

extern "C" void kernel_launch(void* const* d_in, const int* in_sizes, int n_in,
                              void* d_out, int out_size, void* d_ws, size_t ws_size,
                              hipStream_t stream) {
    const int*   x1 = (const int*)d_in[0];
    const int*   x2 = (const int*)d_in[1];
    const float* w  = (const float*)d_in[2];
    float*       out = (float*)d_out;

    const int T1 = in_sizes[0] / L_LEVELS;
    const int T2 = in_sizes[1] / L_LEVELS;
    const int Ttot = T1 + T2;

    multi_embed_kernel<<<Ttot, 256, 0, stream>>>(x1, x2, w, out, T1, Ttot);
}